// Round 1
// baseline (2349.422 us; speedup 1.0000x reference)
//
#include <hip/hip_runtime.h>
#include <hip/hip_bf16.h>
#include <math.h>

typedef __bf16 bf16x8_t __attribute__((ext_vector_type(8)));
typedef float f32x4_t __attribute__((ext_vector_type(4)));
typedef __hip_bfloat16 bf16;

// ---------------- fp32 -> bf16 convert ----------------
__global__ __launch_bounds__(256) void f2b_kernel(const float* __restrict__ in,
                                                  bf16* __restrict__ out, size_t n) {
  size_t i = ((size_t)blockIdx.x * 256 + threadIdx.x) * 4;
  if (i + 4 <= n) {
    float4 v = *reinterpret_cast<const float4*>(in + i);
    union { bf16 b[4]; ushort4 u; } cv;
    cv.b[0] = __float2bfloat16(v.x);
    cv.b[1] = __float2bfloat16(v.y);
    cv.b[2] = __float2bfloat16(v.z);
    cv.b[3] = __float2bfloat16(v.w);
    *reinterpret_cast<ushort4*>(out + i) = cv.u;
  } else {
    for (; i < n; ++i) out[i] = __float2bfloat16(in[i]);
  }
}

// ---------------- RMSNorm (fp32 in -> bf16 out) ----------------
__global__ __launch_bounds__(256) void rmsnorm_kernel(const float* __restrict__ in,
                                                      const float* __restrict__ w,
                                                      bf16* __restrict__ out, int C) {
  int row = blockIdx.x;
  const float* r = in + (size_t)row * C;
  int tid = threadIdx.x;
  float ss = 0.f;
  for (int c = tid; c < C; c += 256) { float v = r[c]; ss += v * v; }
#pragma unroll
  for (int o = 32; o > 0; o >>= 1) ss += __shfl_down(ss, o, 64);
  __shared__ float part[4];
  if ((tid & 63) == 0) part[tid >> 6] = ss;
  __syncthreads();
  float inv = rsqrtf((part[0] + part[1] + part[2] + part[3]) / (float)C + 1e-6f);
  bf16* orow = out + (size_t)row * C;
  for (int c = tid; c < C; c += 256) orow[c] = __float2bfloat16(r[c] * inv * w[c]);
}

// ---------------- gather: pad + roll(-shift), split channels ----------------
// xb[b, t', c] = (src=(t'+shift)%Tp) < Tn ? xi[b, src, coff+c] : 0   (c in [0,256))
__global__ __launch_bounds__(256) void gather_kernel(const bf16* __restrict__ xi,
                                                     bf16* __restrict__ xb,
                                                     int Tp, int Tn, int shift, int coff) {
  size_t i = (size_t)blockIdx.x * 256 + threadIdx.x;  // over B*Tp*256
  int c = (int)(i & 255);
  size_t bt = i >> 8;
  int t = (int)(bt % (size_t)Tp);
  int b = (int)(bt / (size_t)Tp);
  int src = t + shift; if (src >= Tp) src -= Tp;
  bf16 v = __float2bfloat16(0.f);
  if (src < Tn) v = xi[(((size_t)b * Tn + src) << 9) + coff + c];
  xb[i] = v;
}

// ---------------- per-window attention (fp32 math, bf16 qkv in / bf16 out) ----
// one thread per (head, query-row); qkv layout (B*Tp, 768) = [q|k|v][h*32+d]
template <int W, int SHIFT>
__global__ void attn_kernel(const bf16* __restrict__ qkv, const float* __restrict__ rpb,
                            bf16* __restrict__ out, int nW, int Tp) {
  int blk = blockIdx.x;
  int b = blk / nW, n = blk % nW;
  int pair = threadIdx.x;
  if (pair >= 8 * W) return;
  int h = pair / W, qi = pair % W;
  size_t base = ((size_t)b * Tp + (size_t)n * W) * 768;
  float qv[32];
#pragma unroll
  for (int d = 0; d < 32; ++d) qv[d] = __bfloat162float(qkv[base + (size_t)qi * 768 + h * 32 + d]);
  const float scale = 0.17677669529663689f;  // 32^-0.5
  float sc[W];
  float mx = -1e30f;
  for (int k = 0; k < W; ++k) {
    const bf16* kr = qkv + base + (size_t)k * 768 + 256 + h * 32;
    float dot = 0.f;
#pragma unroll
    for (int d = 0; d < 32; ++d) dot += qv[d] * __bfloat162float(kr[d]);
    float s = dot * scale + rpb[(qi - k + W - 1) * 8 + h];
    if (n == nW - 1) {  // only last window has the shift mask
      bool lq = qi < (W - SHIFT), lk = k < (W - SHIFT);
      if (lq != lk) s -= 100.0f;
    }
    sc[k] = s;
    mx = fmaxf(mx, s);
  }
  float l = 0.f;
  for (int k = 0; k < W; ++k) { sc[k] = expf(sc[k] - mx); l += sc[k]; }
  float inv = 1.0f / l;
  float ov[32];
#pragma unroll
  for (int d = 0; d < 32; ++d) ov[d] = 0.f;
  for (int k = 0; k < W; ++k) {
    const bf16* vr = qkv + base + (size_t)k * 768 + 512 + h * 32;
    float p = sc[k];
#pragma unroll
    for (int d = 0; d < 32; ++d) ov[d] += p * __bfloat162float(vr[d]);
  }
  bf16* orow = out + ((size_t)b * Tp + (size_t)n * W + qi) * 256 + h * 32;
#pragma unroll
  for (int d = 0; d < 32; ++d) orow[d] = __float2bfloat16(ov[d] * inv);
}

// ---------------- generic bf16 MFMA GEMM: C = A(MxK) @ W(KxN) + bias -------
// MODE 0: fp32 out          MODE 1: bf16 out
// MODE 2: fp32 out = acc + bias + resid   (resid/outF may alias)
// MODE 3: bf16 out = gelu_exact(acc + bias)
// MODE 5: bf16 scatter with inverse roll: row (b,t') -> out[b, (t'+shift)%Tp] if < Tn,
//         at column offset coff in a row of ldc.
template <int MODE>
__global__ __launch_bounds__(256) void gemm_kernel(
    const bf16* __restrict__ A, const bf16* __restrict__ Wm,
    const float* __restrict__ bias,
    float* outF, bf16* outB, const float* resid,
    int M, int N, int K, int ldc, int Tp, int Tn, int shift, int coff) {
  __shared__ alignas(16) unsigned short lA[64][40];  // [m][k], padded stride 40
  __shared__ alignas(16) unsigned short lB[64][40];  // [n][k] (transposed), padded
  int tid = threadIdx.x;
  int wave = tid >> 6, lane = tid & 63;
  int wm = (wave >> 1) * 32, wn = (wave & 1) * 32;
  int m0 = blockIdx.y * 64, n0 = blockIdx.x * 64;
  f32x4_t acc[2][2] = {};

  int la_r = tid >> 2, la_c = (tid & 3) * 8;  // A staging: 64 rows x 32 cols
  int lb_r = tid >> 3, lb_c = (tid & 7) * 8;  // B staging: 32 k-rows x 64 n-cols
  int arow = m0 + la_r;
  const int koff = (lane >> 4) * 8;
  const int ml = lane & 15;

  for (int k0 = 0; k0 < K; k0 += 32) {
    __syncthreads();
    uint4 av = make_uint4(0u, 0u, 0u, 0u);
    if (arow < M)
      av = *reinterpret_cast<const uint4*>(A + (size_t)arow * K + k0 + la_c);
    *reinterpret_cast<uint4*>(&lA[la_r][la_c]) = av;

    uint4 bv = *reinterpret_cast<const uint4*>(Wm + (size_t)(k0 + lb_r) * N + n0 + lb_c);
    const unsigned short* bw = reinterpret_cast<const unsigned short*>(&bv);
#pragma unroll
    for (int j = 0; j < 8; ++j) lB[lb_c + j][lb_r] = bw[j];
    __syncthreads();

    bf16x8_t a0 = *reinterpret_cast<const bf16x8_t*>(&lA[wm + ml][koff]);
    bf16x8_t a1 = *reinterpret_cast<const bf16x8_t*>(&lA[wm + 16 + ml][koff]);
    bf16x8_t b0 = *reinterpret_cast<const bf16x8_t*>(&lB[wn + ml][koff]);
    bf16x8_t b1 = *reinterpret_cast<const bf16x8_t*>(&lB[wn + 16 + ml][koff]);
    acc[0][0] = __builtin_amdgcn_mfma_f32_16x16x32_bf16(a0, b0, acc[0][0], 0, 0, 0);
    acc[0][1] = __builtin_amdgcn_mfma_f32_16x16x32_bf16(a0, b1, acc[0][1], 0, 0, 0);
    acc[1][0] = __builtin_amdgcn_mfma_f32_16x16x32_bf16(a1, b0, acc[1][0], 0, 0, 0);
    acc[1][1] = __builtin_amdgcn_mfma_f32_16x16x32_bf16(a1, b1, acc[1][1], 0, 0, 0);
  }

  int rbase = (lane >> 4) * 4;
#pragma unroll
  for (int mt = 0; mt < 2; ++mt)
#pragma unroll
    for (int nt = 0; nt < 2; ++nt)
#pragma unroll
      for (int i = 0; i < 4; ++i) {
        int row = m0 + wm + mt * 16 + rbase + i;
        int col = n0 + wn + nt * 16 + ml;
        if (row >= M) continue;
        float v = acc[mt][nt][i] + bias[col];
        if (MODE == 0) {
          outF[(size_t)row * ldc + col] = v;
        } else if (MODE == 1) {
          outB[(size_t)row * ldc + col] = __float2bfloat16(v);
        } else if (MODE == 2) {
          outF[(size_t)row * ldc + col] = v + resid[(size_t)row * ldc + col];
        } else if (MODE == 3) {
          v = 0.5f * v * (1.0f + erff(v * 0.70710678118654752f));
          outB[(size_t)row * ldc + col] = __float2bfloat16(v);
        } else if (MODE == 5) {
          int b = row / Tp;
          int t = row - b * Tp;
          int i2 = t + shift; if (i2 >= Tp) i2 -= Tp;
          if (i2 < Tn)
            outB[((size_t)b * Tn + i2) * ldc + coff + col] = __float2bfloat16(v);
        }
      }
}

extern "C" void kernel_launch(void* const* d_in, const int* in_sizes, int n_in,
                              void* d_out, int out_size, void* d_ws, size_t ws_size,
                              hipStream_t stream) {
  const float* x       = (const float*)d_in[0];
  const float* down_w  = (const float*)d_in[1];
  const float* down_b  = (const float*)d_in[2];
  const float* up_w    = (const float*)d_in[3];
  const float* up_b    = (const float*)d_in[4];
  const float* norm1_w = (const float*)d_in[5];
  const float* norm2_w = (const float*)d_in[6];
  const float* qkv1_w  = (const float*)d_in[7];
  const float* qkv1_b  = (const float*)d_in[8];
  const float* proj1_w = (const float*)d_in[9];
  const float* proj1_b = (const float*)d_in[10];
  const float* rpb1    = (const float*)d_in[11];
  const float* qkv2_w  = (const float*)d_in[12];
  const float* qkv2_b  = (const float*)d_in[13];
  const float* proj2_w = (const float*)d_in[14];
  const float* proj2_b = (const float*)d_in[15];
  const float* rpb2    = (const float*)d_in[16];
  const float* ffn_w1  = (const float*)d_in[17];
  const float* ffn_b1  = (const float*)d_in[18];
  const float* ffn_w2  = (const float*)d_in[19];
  const float* ffn_b2  = (const float*)d_in[20];
  float* out = (float*)d_out;

  const int Bb = 8, T = 4096, DIM = 1024, DIM_IN = 512;
  const int Tp = 4100, Tn = T;
  const int M  = Bb * T;   // 32768
  const int Mp = Bb * Tp;  // 32800
  const int nW1 = Tp / 10, nW2 = Tp / 20;  // 410, 205

  char* ws = (char*)d_ws;
  const size_t MB = 1ull << 20;
  // weights bf16 at [0, 12MiB)
  size_t wo = 0;
  auto walloc = [&](size_t elems) {
    bf16* p = (bf16*)(ws + wo);
    wo += ((elems * 2 + 255) & ~(size_t)255);
    return p;
  };
  bf16* w_down  = walloc(1024 * 512);
  bf16* w_up    = walloc(512 * 1024);
  bf16* w_qkv1  = walloc(256 * 768);
  bf16* w_proj1 = walloc(256 * 256);
  bf16* w_qkv2  = walloc(256 * 768);
  bf16* w_proj2 = walloc(256 * 256);
  bf16* w_ffn1  = walloc(1024 * 2048);
  bf16* w_ffn2  = walloc(2048 * 1024);
  // overlapped scratch regions (lifetimes disjoint):
  bf16*  xbf     = (bf16*)(ws + 12 * MB);   // [12,76)  x in bf16 (down gemm only)
  bf16*  xb1     = (bf16*)(ws + 12 * MB);   // [12,29)  after xbf dead
  bf16*  xb2     = (bf16*)(ws + 29 * MB);   // [29,46)
  bf16*  att1    = (bf16*)(ws + 46 * MB);   // [46,63)
  bf16*  att2    = (bf16*)(ws + 63 * MB);   // [63,80)
  float* y1      = (float*)(ws + 80 * MB);  // [80,144) down-gemm fp32 out
  bf16*  concatb = (bf16*)(ws + 80 * MB);   // [80,112) after y1 dead
  bf16*  hbuf    = (bf16*)(ws + 80 * MB);   // [80,144) after concat dead
  bf16*  xi      = (bf16*)(ws + 144 * MB);  // [144,176)
  bf16*  qkv1buf = (bf16*)(ws + 176 * MB);  // [176,225)
  bf16*  qkv2buf = (bf16*)(ws + 225 * MB);  // [225,274)
  bf16*  gbuf    = (bf16*)(ws + 144 * MB);  // [144,272) after xi/qkv dead

  auto cvt = [&](const float* src, bf16* dst, size_t n) {
    int grid = (int)((n / 4 + 255) / 256);
    hipLaunchKernelGGL(f2b_kernel, dim3(grid), dim3(256), 0, stream, src, dst, n);
  };
  cvt(x, xbf, (size_t)M * DIM);
  cvt(down_w, w_down, 1024 * 512);
  cvt(up_w, w_up, 512 * 1024);
  cvt(qkv1_w, w_qkv1, 256 * 768);
  cvt(proj1_w, w_proj1, 256 * 256);
  cvt(qkv2_w, w_qkv2, 256 * 768);
  cvt(proj2_w, w_proj2, 256 * 256);
  cvt(ffn_w1, w_ffn1, 1024 * 2048);
  cvt(ffn_w2, w_ffn2, 2048 * 1024);

  // down: y1 = x @ down_w + down_b   (fp32 out)
  hipLaunchKernelGGL((gemm_kernel<0>), dim3(DIM_IN / 64, (M + 63) / 64), dim3(256), 0, stream,
                     xbf, w_down, down_b, y1, (bf16*)nullptr, (const float*)nullptr,
                     M, DIM_IN, DIM, DIM_IN, 0, 0, 0, 0);
  // xi = rmsnorm(y1) (bf16)
  hipLaunchKernelGGL(rmsnorm_kernel, dim3(M), dim3(256), 0, stream, y1, norm1_w, xi, DIM_IN);
  // gathers: pad+roll
  hipLaunchKernelGGL(gather_kernel, dim3(Mp), dim3(256), 0, stream, xi, xb1, Tp, Tn, 5, 0);
  hipLaunchKernelGGL(gather_kernel, dim3(Mp), dim3(256), 0, stream, xi, xb2, Tp, Tn, 10, 256);
  // qkv gemms (bf16 out)
  hipLaunchKernelGGL((gemm_kernel<1>), dim3(768 / 64, (Mp + 63) / 64), dim3(256), 0, stream,
                     xb1, w_qkv1, qkv1_b, (float*)nullptr, qkv1buf, (const float*)nullptr,
                     Mp, 768, 256, 768, 0, 0, 0, 0);
  hipLaunchKernelGGL((gemm_kernel<1>), dim3(768 / 64, (Mp + 63) / 64), dim3(256), 0, stream,
                     xb2, w_qkv2, qkv2_b, (float*)nullptr, qkv2buf, (const float*)nullptr,
                     Mp, 768, 256, 768, 0, 0, 0, 0);
  // window attention
  hipLaunchKernelGGL((attn_kernel<10, 5>), dim3(Bb * nW1), dim3(128), 0, stream,
                     qkv1buf, rpb1, att1, nW1, Tp);
  hipLaunchKernelGGL((attn_kernel<20, 10>), dim3(Bb * nW2), dim3(192), 0, stream,
                     qkv2buf, rpb2, att2, nW2, Tp);
  // proj gemms with inverse-roll scatter into concat buffer (ldc=512)
  hipLaunchKernelGGL((gemm_kernel<5>), dim3(256 / 64, (Mp + 63) / 64), dim3(256), 0, stream,
                     att1, w_proj1, proj1_b, (float*)nullptr, concatb, (const float*)nullptr,
                     Mp, 256, 256, 512, Tp, Tn, 5, 0);
  hipLaunchKernelGGL((gemm_kernel<5>), dim3(256 / 64, (Mp + 63) / 64), dim3(256), 0, stream,
                     att2, w_proj2, proj2_b, (float*)nullptr, concatb, (const float*)nullptr,
                     Mp, 256, 256, 512, Tp, Tn, 10, 256);
  // up: d_out = residual(x) + concat @ up_w + up_b  (fp32, this is xnew)
  hipLaunchKernelGGL((gemm_kernel<2>), dim3(DIM / 64, (M + 63) / 64), dim3(256), 0, stream,
                     concatb, w_up, up_b, out, (bf16*)nullptr, x,
                     M, DIM, DIM_IN, DIM, 0, 0, 0, 0);
  // h = rmsnorm(xnew)
  hipLaunchKernelGGL(rmsnorm_kernel, dim3(M), dim3(256), 0, stream, out, norm2_w, hbuf, DIM);
  // ffn1: g = gelu(h @ w1 + b1)  (bf16)
  hipLaunchKernelGGL((gemm_kernel<3>), dim3(2048 / 64, (M + 63) / 64), dim3(256), 0, stream,
                     hbuf, w_ffn1, ffn_b1, (float*)nullptr, gbuf, (const float*)nullptr,
                     M, 2048, DIM, 2048, 0, 0, 0, 0);
  // ffn2: d_out = d_out + g @ w2 + b2  (in-place residual)
  hipLaunchKernelGGL((gemm_kernel<2>), dim3(DIM / 64, (M + 63) / 64), dim3(256), 0, stream,
                     gbuf, w_ffn2, ffn_b2, out, (bf16*)nullptr, out,
                     M, DIM, 2048, DIM, 0, 0, 0, 0);
  (void)in_sizes; (void)n_in; (void)out_size; (void)ws_size;
}

// Round 2
// 1543.586 us; speedup vs baseline: 1.5221x; 1.5221x over previous
//
#include <hip/hip_runtime.h>
#include <hip/hip_bf16.h>
#include <math.h>

typedef __bf16 bf16x8_t __attribute__((ext_vector_type(8)));
typedef float f32x4_t __attribute__((ext_vector_type(4)));
typedef __hip_bfloat16 bf16;

// async global -> LDS, 16B per lane, wave-uniform LDS base + lane*16
__device__ __forceinline__ void gload_lds16(const bf16* gsrc, unsigned short* ldst) {
  __builtin_amdgcn_global_load_lds(
      (const __attribute__((address_space(1))) unsigned int*)gsrc,
      (__attribute__((address_space(3))) unsigned int*)ldst, 16, 0, 0);
}

// ---------------- fp32 -> bf16 convert ----------------
__global__ __launch_bounds__(256) void f2b_kernel(const float* __restrict__ in,
                                                  bf16* __restrict__ out, size_t n) {
  size_t i = ((size_t)blockIdx.x * 256 + threadIdx.x) * 4;
  if (i + 4 <= n) {
    float4 v = *reinterpret_cast<const float4*>(in + i);
    union { bf16 b[4]; ushort4 u; } cv;
    cv.b[0] = __float2bfloat16(v.x);
    cv.b[1] = __float2bfloat16(v.y);
    cv.b[2] = __float2bfloat16(v.z);
    cv.b[3] = __float2bfloat16(v.w);
    *reinterpret_cast<ushort4*>(out + i) = cv.u;
  } else {
    for (; i < n; ++i) out[i] = __float2bfloat16(in[i]);
  }
}

// ---------------- fp32 [K][N] -> bf16 transposed [N][K] ----------------
__global__ __launch_bounds__(256) void transpose_f2b_kernel(const float* __restrict__ in,
                                                            bf16* __restrict__ out,
                                                            int K, int N) {
  __shared__ float t[32][33];
  int n0 = blockIdx.x * 32, k0 = blockIdx.y * 32;
  int tx = threadIdx.x & 31, ty = threadIdx.x >> 5;  // 32 x 8
#pragma unroll
  for (int i = 0; i < 32; i += 8)
    t[ty + i][tx] = in[(size_t)(k0 + ty + i) * N + n0 + tx];
  __syncthreads();
#pragma unroll
  for (int i = 0; i < 32; i += 8)
    out[(size_t)(n0 + ty + i) * K + k0 + tx] = __float2bfloat16(t[tx][ty + i]);
}

// ---------------- RMSNorm (fp32 in -> bf16 out) ----------------
__global__ __launch_bounds__(256) void rmsnorm_kernel(const float* __restrict__ in,
                                                      const float* __restrict__ w,
                                                      bf16* __restrict__ out, int C) {
  int row = blockIdx.x;
  const float* r = in + (size_t)row * C;
  int tid = threadIdx.x;
  float ss = 0.f;
  for (int c = tid; c < C; c += 256) { float v = r[c]; ss += v * v; }
#pragma unroll
  for (int o = 32; o > 0; o >>= 1) ss += __shfl_down(ss, o, 64);
  __shared__ float part[4];
  if ((tid & 63) == 0) part[tid >> 6] = ss;
  __syncthreads();
  float inv = rsqrtf((part[0] + part[1] + part[2] + part[3]) / (float)C + 1e-6f);
  bf16* orow = out + (size_t)row * C;
  for (int c = tid; c < C; c += 256) orow[c] = __float2bfloat16(r[c] * inv * w[c]);
}

// ---------------- gather: pad + roll(-shift), split channels ----------------
__global__ __launch_bounds__(256) void gather_kernel(const bf16* __restrict__ xi,
                                                     bf16* __restrict__ xb,
                                                     int Tp, int Tn, int shift, int coff) {
  size_t i = (size_t)blockIdx.x * 256 + threadIdx.x;  // over B*Tp*256
  int c = (int)(i & 255);
  size_t bt = i >> 8;
  int t = (int)(bt % (size_t)Tp);
  int b = (int)(bt / (size_t)Tp);
  int src = t + shift; if (src >= Tp) src -= Tp;
  bf16 v = __float2bfloat16(0.f);
  if (src < Tn) v = xi[(((size_t)b * Tn + src) << 9) + coff + c];
  xb[i] = v;
}

// ---------------- per-window attention (fp32 math, bf16 qkv in / bf16 out) ----
template <int W, int SHIFT>
__global__ void attn_kernel(const bf16* __restrict__ qkv, const float* __restrict__ rpb,
                            bf16* __restrict__ out, int nW, int Tp) {
  int blk = blockIdx.x;
  int b = blk / nW, n = blk % nW;
  int pair = threadIdx.x;
  if (pair >= 8 * W) return;
  int h = pair / W, qi = pair % W;
  size_t base = ((size_t)b * Tp + (size_t)n * W) * 768;
  float qv[32];
#pragma unroll
  for (int d = 0; d < 32; ++d) qv[d] = __bfloat162float(qkv[base + (size_t)qi * 768 + h * 32 + d]);
  const float scale = 0.17677669529663689f;
  float sc[W];
  float mx = -1e30f;
  for (int k = 0; k < W; ++k) {
    const bf16* kr = qkv + base + (size_t)k * 768 + 256 + h * 32;
    float dot = 0.f;
#pragma unroll
    for (int d = 0; d < 32; ++d) dot += qv[d] * __bfloat162float(kr[d]);
    float s = dot * scale + rpb[(qi - k + W - 1) * 8 + h];
    if (n == nW - 1) {
      bool lq = qi < (W - SHIFT), lk = k < (W - SHIFT);
      if (lq != lk) s -= 100.0f;
    }
    sc[k] = s;
    mx = fmaxf(mx, s);
  }
  float l = 0.f;
  for (int k = 0; k < W; ++k) { sc[k] = expf(sc[k] - mx); l += sc[k]; }
  float inv = 1.0f / l;
  float ov[32];
#pragma unroll
  for (int d = 0; d < 32; ++d) ov[d] = 0.f;
  for (int k = 0; k < W; ++k) {
    const bf16* vr = qkv + base + (size_t)k * 768 + 512 + h * 32;
    float p = sc[k];
#pragma unroll
    for (int d = 0; d < 32; ++d) ov[d] += p * __bfloat162float(vr[d]);
  }
  bf16* orow = out + ((size_t)b * Tp + (size_t)n * W + qi) * 256 + h * 32;
#pragma unroll
  for (int d = 0; d < 32; ++d) orow[d] = __float2bfloat16(ov[d] * inv);
}

// ---------------- 128x128 MFMA GEMM: C = A(MxK) @ Wt^T + bias --------------
// A: [M][K] bf16 row-major.  Wt: [N][K] bf16 row-major (pre-transposed weight).
// BK=32, 4 waves, each computes 64x64 (4x4 frags of 16x16x32).
// global_load_lds width=16 staging (m97 structure).
// MODE 0: fp32 out   MODE 1: bf16 out
// MODE 2: fp32 out = acc + bias + resid  (resid may alias outF)
// MODE 3: bf16 out = gelu_exact(acc + bias)
// MODE 5: bf16 scatter, inverse roll: row (b,t') -> out[b, (t'+shift)%Tp] if < Tn, col+coff
template <int MODE>
__global__ __launch_bounds__(256) void gemm_kernel(
    const bf16* __restrict__ A, const bf16* __restrict__ Wt,
    const float* __restrict__ bias,
    float* outF, bf16* outB, const float* resid,
    int M, int N, int K, int ldc, int Tp, int Tn, int shift, int coff) {
  __shared__ unsigned short lA[128 * 32];
  __shared__ unsigned short lB[128 * 32];
  int tid = threadIdx.x;
  int wave = tid >> 6, lane = tid & 63;
  int m0 = blockIdx.y * 128, n0 = blockIdx.x * 128;
  int wm = (wave >> 1) * 64, wn = (wave & 1) * 64;
  int ml = lane & 15, koff = (lane >> 4) * 8;
  f32x4_t acc[4][4] = {};

  int lrow = lane >> 2;        // 0..15 (row within a 16-row chunk)
  int lcol = (lane & 3) * 8;   // k-offset in elements
  int ar0 = wave * 32;         // each wave stages rows [ar0, ar0+32) of both tiles

  for (int k0 = 0; k0 < K; k0 += 32) {
    __syncthreads();
#pragma unroll
    for (int j = 0; j < 2; ++j) {
      int r = ar0 + j * 16;
      int gr = m0 + r + lrow; if (gr > M - 1) gr = M - 1;  // clamp; garbage rows masked at store
      gload_lds16(A + (size_t)gr * K + k0 + lcol, &lA[r * 32]);
      int nr = n0 + r + lrow;  // N is a multiple of 128 for all our GEMMs
      gload_lds16(Wt + (size_t)nr * K + k0 + lcol, &lB[r * 32]);
    }
    __syncthreads();

    bf16x8_t fa[4], fb[4];
#pragma unroll
    for (int t = 0; t < 4; ++t) {
      fa[t] = *reinterpret_cast<const bf16x8_t*>(&lA[(wm + t * 16 + ml) * 32 + koff]);
      fb[t] = *reinterpret_cast<const bf16x8_t*>(&lB[(wn + t * 16 + ml) * 32 + koff]);
    }
#pragma unroll
    for (int mt = 0; mt < 4; ++mt)
#pragma unroll
      for (int nt = 0; nt < 4; ++nt)
        acc[mt][nt] = __builtin_amdgcn_mfma_f32_16x16x32_bf16(fa[mt], fb[nt], acc[mt][nt], 0, 0, 0);
  }

  int rbase = (lane >> 4) * 4;
#pragma unroll
  for (int mt = 0; mt < 4; ++mt)
#pragma unroll
    for (int nt = 0; nt < 4; ++nt)
#pragma unroll
      for (int i = 0; i < 4; ++i) {
        int row = m0 + wm + mt * 16 + rbase + i;
        int col = n0 + wn + nt * 16 + ml;
        if (row >= M) continue;
        float v = acc[mt][nt][i] + bias[col];
        if (MODE == 0) {
          outF[(size_t)row * ldc + col] = v;
        } else if (MODE == 1) {
          outB[(size_t)row * ldc + col] = __float2bfloat16(v);
        } else if (MODE == 2) {
          outF[(size_t)row * ldc + col] = v + resid[(size_t)row * ldc + col];
        } else if (MODE == 3) {
          v = 0.5f * v * (1.0f + erff(v * 0.70710678118654752f));
          outB[(size_t)row * ldc + col] = __float2bfloat16(v);
        } else if (MODE == 5) {
          int b = row / Tp;
          int t = row - b * Tp;
          int i2 = t + shift; if (i2 >= Tp) i2 -= Tp;
          if (i2 < Tn)
            outB[((size_t)b * Tn + i2) * ldc + coff + col] = __float2bfloat16(v);
        }
      }
}

extern "C" void kernel_launch(void* const* d_in, const int* in_sizes, int n_in,
                              void* d_out, int out_size, void* d_ws, size_t ws_size,
                              hipStream_t stream) {
  const float* x       = (const float*)d_in[0];
  const float* down_w  = (const float*)d_in[1];
  const float* down_b  = (const float*)d_in[2];
  const float* up_w    = (const float*)d_in[3];
  const float* up_b    = (const float*)d_in[4];
  const float* norm1_w = (const float*)d_in[5];
  const float* norm2_w = (const float*)d_in[6];
  const float* qkv1_w  = (const float*)d_in[7];
  const float* qkv1_b  = (const float*)d_in[8];
  const float* proj1_w = (const float*)d_in[9];
  const float* proj1_b = (const float*)d_in[10];
  const float* rpb1    = (const float*)d_in[11];
  const float* qkv2_w  = (const float*)d_in[12];
  const float* qkv2_b  = (const float*)d_in[13];
  const float* proj2_w = (const float*)d_in[14];
  const float* proj2_b = (const float*)d_in[15];
  const float* rpb2    = (const float*)d_in[16];
  const float* ffn_w1  = (const float*)d_in[17];
  const float* ffn_b1  = (const float*)d_in[18];
  const float* ffn_w2  = (const float*)d_in[19];
  const float* ffn_b2  = (const float*)d_in[20];
  float* out = (float*)d_out;

  const int Bb = 8, T = 4096, DIM = 1024, DIM_IN = 512;
  const int Tp = 4100, Tn = T;
  const int M  = Bb * T;   // 32768
  const int Mp = Bb * Tp;  // 32800
  const int nW1 = Tp / 10, nW2 = Tp / 20;

  char* ws = (char*)d_ws;
  const size_t MB = 1ull << 20;
  size_t wo = 0;
  auto walloc = [&](size_t elems) {
    bf16* p = (bf16*)(ws + wo);
    wo += ((elems * 2 + 255) & ~(size_t)255);
    return p;
  };
  // transposed bf16 weights [N][K]
  bf16* w_down  = walloc(1024 * 512);
  bf16* w_up    = walloc(512 * 1024);
  bf16* w_qkv1  = walloc(256 * 768);
  bf16* w_proj1 = walloc(256 * 256);
  bf16* w_qkv2  = walloc(256 * 768);
  bf16* w_proj2 = walloc(256 * 256);
  bf16* w_ffn1  = walloc(1024 * 2048);
  bf16* w_ffn2  = walloc(2048 * 1024);
  // overlapped scratch:
  bf16*  xbf     = (bf16*)(ws + 12 * MB);   // x bf16 (down gemm only)
  bf16*  xb1     = (bf16*)(ws + 12 * MB);   // after xbf dead
  bf16*  xb2     = (bf16*)(ws + 29 * MB);
  bf16*  att1    = (bf16*)(ws + 46 * MB);
  bf16*  att2    = (bf16*)(ws + 63 * MB);
  float* y1      = (float*)(ws + 80 * MB);  // down fp32 out
  bf16*  concatb = (bf16*)(ws + 80 * MB);   // after y1 dead
  bf16*  hbuf    = (bf16*)(ws + 80 * MB);   // after concat dead
  bf16*  xi      = (bf16*)(ws + 144 * MB);
  bf16*  qkv1buf = (bf16*)(ws + 176 * MB);
  bf16*  qkv2buf = (bf16*)(ws + 225 * MB);
  bf16*  gbuf    = (bf16*)(ws + 144 * MB);  // after xi/qkv dead

  auto cvt = [&](const float* src, bf16* dst, size_t n) {
    int grid = (int)((n / 4 + 255) / 256);
    hipLaunchKernelGGL(f2b_kernel, dim3(grid), dim3(256), 0, stream, src, dst, n);
  };
  auto tr = [&](const float* src, bf16* dst, int K, int N) {
    hipLaunchKernelGGL(transpose_f2b_kernel, dim3(N / 32, K / 32), dim3(256), 0, stream,
                       src, dst, K, N);
  };
  cvt(x, xbf, (size_t)M * DIM);
  tr(down_w, w_down, 1024, 512);
  tr(up_w, w_up, 512, 1024);
  tr(qkv1_w, w_qkv1, 256, 768);
  tr(proj1_w, w_proj1, 256, 256);
  tr(qkv2_w, w_qkv2, 256, 768);
  tr(proj2_w, w_proj2, 256, 256);
  tr(ffn_w1, w_ffn1, 1024, 2048);
  tr(ffn_w2, w_ffn2, 2048, 1024);

  auto gemm = [&](auto modeTag, const bf16* A, const bf16* Wt, const float* bias,
                  float* oF, bf16* oB, const float* res,
                  int Mm, int Nn, int Kk, int ldc, int tp, int tn, int sh, int co) {
    constexpr int MODE = decltype(modeTag)::value;
    hipLaunchKernelGGL((gemm_kernel<MODE>), dim3(Nn / 128, (Mm + 127) / 128), dim3(256), 0,
                       stream, A, Wt, bias, oF, oB, res, Mm, Nn, Kk, ldc, tp, tn, sh, co);
  };
  using I0 = std::integral_constant<int, 0>;
  using I1 = std::integral_constant<int, 1>;
  using I2 = std::integral_constant<int, 2>;
  using I3 = std::integral_constant<int, 3>;
  using I5 = std::integral_constant<int, 5>;

  // down: y1 = x @ down_w + down_b (fp32)
  gemm(I0{}, xbf, w_down, down_b, y1, nullptr, nullptr, M, DIM_IN, DIM, DIM_IN, 0, 0, 0, 0);
  hipLaunchKernelGGL(rmsnorm_kernel, dim3(M), dim3(256), 0, stream, y1, norm1_w, xi, DIM_IN);
  hipLaunchKernelGGL(gather_kernel, dim3(Mp), dim3(256), 0, stream, xi, xb1, Tp, Tn, 5, 0);
  hipLaunchKernelGGL(gather_kernel, dim3(Mp), dim3(256), 0, stream, xi, xb2, Tp, Tn, 10, 256);
  gemm(I1{}, xb1, w_qkv1, qkv1_b, nullptr, qkv1buf, nullptr, Mp, 768, 256, 768, 0, 0, 0, 0);
  gemm(I1{}, xb2, w_qkv2, qkv2_b, nullptr, qkv2buf, nullptr, Mp, 768, 256, 768, 0, 0, 0, 0);
  hipLaunchKernelGGL((attn_kernel<10, 5>), dim3(Bb * nW1), dim3(128), 0, stream,
                     qkv1buf, rpb1, att1, nW1, Tp);
  hipLaunchKernelGGL((attn_kernel<20, 10>), dim3(Bb * nW2), dim3(192), 0, stream,
                     qkv2buf, rpb2, att2, nW2, Tp);
  gemm(I5{}, att1, w_proj1, proj1_b, nullptr, concatb, nullptr, Mp, 256, 256, 512, Tp, Tn, 5, 0);
  gemm(I5{}, att2, w_proj2, proj2_b, nullptr, concatb, nullptr, Mp, 256, 256, 512, Tp, Tn, 10, 256);
  // up: out = x + concat @ up_w + up_b (fp32, xnew)
  gemm(I2{}, concatb, w_up, up_b, out, nullptr, x, M, DIM, DIM_IN, DIM, 0, 0, 0, 0);
  hipLaunchKernelGGL(rmsnorm_kernel, dim3(M), dim3(256), 0, stream, out, norm2_w, hbuf, DIM);
  gemm(I3{}, hbuf, w_ffn1, ffn_b1, nullptr, gbuf, nullptr, M, 2048, DIM, 2048, 0, 0, 0, 0);
  gemm(I2{}, gbuf, w_ffn2, ffn_b2, out, nullptr, out, M, DIM, 2048, DIM, 0, 0, 0, 0);
  (void)in_sizes; (void)n_in; (void)out_size; (void)ws_size;
}